// Round 4
// baseline (1019.624 us; speedup 1.0000x reference)
//
#include <hip/hip_runtime.h>
#include <hip/hip_bf16.h>

#define N_NODES 12288
#define N_EDGES 393216

typedef __attribute__((ext_vector_type(8))) short bf16x8;
typedef __attribute__((ext_vector_type(4))) float f32x4;

// ---------------- edge-width detection ----------------
// Reference edge_index is int64. If the harness passes raw int64, every odd
// 32-bit word of the first E pairs is the (zero) high word. If it converted
// to int32, those words are random src values (all-zero is impossible).
// flag==0 after this kernel  =>  wide (int64) layout.

__global__ __launch_bounds__(256) void detect_kernel(const unsigned* __restrict__ w,
                                                     unsigned* __restrict__ flag) {
  int i = blockIdx.x * 256 + threadIdx.x;          // [0, N_EDGES)
  unsigned v = w[2 * i + 1];
  unsigned long long b = __ballot(v != 0);
  if ((threadIdx.x & 63) == 0 && b) atomicOr(flag, 1u);
}

// ---------------- graph prep ----------------

__global__ __launch_bounds__(256) void count_kernel(const int* __restrict__ ei,
                                                    const unsigned* __restrict__ flag,
                                                    int* __restrict__ cnt) {
  const bool wide = (*flag == 0);
  int e = blockIdx.x * 256 + threadIdx.x;
  int d = wide ? ei[2 * (N_EDGES + e)] : ei[N_EDGES + e];
  atomicAdd(&cnt[d], 1);
}

// single block: exclusive scan of cnt -> csr_off, copy to cursor, and degree terms
__global__ __launch_bounds__(1024) void scan_kernel(const int* __restrict__ cnt,
                                                    int* __restrict__ csr_off,
                                                    int* __restrict__ cursor,
                                                    float* __restrict__ dinv_sqrt,
                                                    float* __restrict__ deg_inv) {
  __shared__ int sdata[1024];
  const int tid = threadIdx.x;
  int carry = 0;
  for (int base = 0; base < N_NODES; base += 1024) {
    int i = base + tid;
    int c = (i < N_NODES) ? cnt[i] : 0;
    if (i < N_NODES) {
      float d = (float)(c + 1);            // deg includes self-loop
      dinv_sqrt[i] = rsqrtf(d);
      deg_inv[i] = 1.0f / d;
    }
    sdata[tid] = c;
    __syncthreads();
    for (int off = 1; off < 1024; off <<= 1) {
      int v = (tid >= off) ? sdata[tid - off] : 0;
      __syncthreads();
      sdata[tid] += v;
      __syncthreads();
    }
    int incl = sdata[tid];
    if (i < N_NODES) {
      int excl = carry + incl - c;
      csr_off[i] = excl;
      cursor[i] = excl;
    }
    int total = sdata[1023];
    __syncthreads();
    carry += total;
  }
  if (tid == 0) csr_off[N_NODES] = carry;
}

__global__ __launch_bounds__(256) void scatter_kernel(const int* __restrict__ ei,
                                                      const unsigned* __restrict__ flag,
                                                      const float* __restrict__ dinv_sqrt,
                                                      int* __restrict__ cursor,
                                                      int* __restrict__ csr_src,
                                                      float* __restrict__ csr_w) {
  const bool wide = (*flag == 0);
  int e = blockIdx.x * 256 + threadIdx.x;
  int s = wide ? ei[2 * e] : ei[e];
  int d = wide ? ei[2 * (N_EDGES + e)] : ei[N_EDGES + e];
  int p = atomicAdd(&cursor[d], 1);
  csr_src[p] = s;
  csr_w[p] = dinv_sqrt[s] * dinv_sqrt[d];
}

// ---------------- dense fp32 GEMM: C[M,Nf] = A[M,K]@B[K,Nf] (+bias, relu) ----------------
// grid = (Nf/64, M/64), block = 256. BM=BN=64, BK=16, 4x4 microtile.

template <bool BIAS, bool RELU>
__global__ __launch_bounds__(256) void gemm_kernel(const float* __restrict__ A,
                                                   const float* __restrict__ B,
                                                   const float* __restrict__ bias,
                                                   float* __restrict__ C,
                                                   int K, int Nf) {
  __shared__ float As[16][65];
  __shared__ float Bs[16][68];
  const int tid = threadIdx.x;
  const int bm = blockIdx.y * 64;
  const int bn = blockIdx.x * 64;
  const int tr = (tid >> 4) * 4;
  const int tc = (tid & 15) * 4;
  const int lm = tid >> 2;          // A-load row 0..63
  const int lk = (tid & 3) * 4;     // A-load k 0,4,8,12
  const int lbk = tid >> 4;         // B-load k 0..15
  const int lbc = (tid & 15) * 4;   // B-load col
  float acc[4][4] = {};
  for (int k0 = 0; k0 < K; k0 += 16) {
    float4 a4 = *reinterpret_cast<const float4*>(&A[(size_t)(bm + lm) * K + k0 + lk]);
    float4 b4 = *reinterpret_cast<const float4*>(&B[(size_t)(k0 + lbk) * Nf + bn + lbc]);
    As[lk + 0][lm] = a4.x; As[lk + 1][lm] = a4.y; As[lk + 2][lm] = a4.z; As[lk + 3][lm] = a4.w;
    Bs[lbk][lbc + 0] = b4.x; Bs[lbk][lbc + 1] = b4.y; Bs[lbk][lbc + 2] = b4.z; Bs[lbk][lbc + 3] = b4.w;
    __syncthreads();
#pragma unroll
    for (int kk = 0; kk < 16; ++kk) {
      float av[4], bv[4];
#pragma unroll
      for (int i = 0; i < 4; ++i) av[i] = As[kk][tr + i];
#pragma unroll
      for (int j = 0; j < 4; ++j) bv[j] = Bs[kk][tc + j];
#pragma unroll
      for (int i = 0; i < 4; ++i)
#pragma unroll
        for (int j = 0; j < 4; ++j) acc[i][j] = fmaf(av[i], bv[j], acc[i][j]);
    }
    __syncthreads();
  }
#pragma unroll
  for (int i = 0; i < 4; ++i) {
    float v[4];
#pragma unroll
    for (int j = 0; j < 4; ++j) {
      float t = acc[i][j];
      if (BIAS) t += bias[bn + tc + j];
      if (RELU) t = fmaxf(t, 0.0f);
      v[j] = t;
    }
    float4 o; o.x = v[0]; o.y = v[1]; o.z = v[2]; o.w = v[3];
    *reinterpret_cast<float4*>(&C[(size_t)(bm + tr + i) * Nf + bn + tc]) = o;
  }
}

// ---------------- GCN aggregation (dst-centric, CSR) ----------------
// out[i,f] = sum_e w_e * H[src_e, f] + deg_inv[i]*H[i,f] (+bias, relu)

template <int F, bool BIAS, bool RELU>
__global__ __launch_bounds__(256) void agg_kernel(const float* __restrict__ H,
                                                  const int* __restrict__ csr_off,
                                                  const int* __restrict__ csr_src,
                                                  const float* __restrict__ csr_w,
                                                  const float* __restrict__ deg_inv,
                                                  const float* __restrict__ bias,
                                                  float* __restrict__ out) {
  constexpr int G = 256 / F;
  const int node = blockIdx.x * G + threadIdx.x / F;
  const int f = threadIdx.x % F;
  const int p0 = csr_off[node];
  const int p1 = csr_off[node + 1];
  float acc = deg_inv[node] * H[(size_t)node * F + f];
  int p = p0;
  for (; p + 1 < p1; p += 2) {
    float w0 = csr_w[p];     int s0 = csr_src[p];
    float w1 = csr_w[p + 1]; int s1 = csr_src[p + 1];
    acc = fmaf(w0, H[(size_t)s0 * F + f], acc);
    acc = fmaf(w1, H[(size_t)s1 * F + f], acc);
  }
  if (p < p1) acc = fmaf(csr_w[p], H[(size_t)csr_src[p] * F + f], acc);
  if (BIAS) acc += bias[f];
  if (RELU) acc = fmaxf(acc, 0.0f);
  out[(size_t)node * F + f] = acc;
}

// ---------------- split s -> bf16 hi/lo ----------------

__device__ __forceinline__ unsigned short f32_to_bf16_rn(float v) {
  unsigned int u = __float_as_uint(v);
  u += 0x7FFFu + ((u >> 16) & 1u);
  return (unsigned short)(u >> 16);
}

__global__ __launch_bounds__(256) void split_kernel(const float* __restrict__ s,
                                                    unsigned short* __restrict__ hi,
                                                    unsigned short* __restrict__ lo) {
  int i = blockIdx.x * 256 + threadIdx.x;  // grid covers N*64 exactly
  float v = s[i];
  unsigned short h = f32_to_bf16_rn(v);
  float hf = __uint_as_float(((unsigned int)h) << 16);
  lo[i] = f32_to_bf16_rn(v - hf);
  hi[i] = h;
}

// ---------------- a_hat = s @ s^T via split-bf16 MFMA ----------------
// block = 256 (4 waves, 2x2), wave computes 64x64; block tile 128x128.

__global__ __launch_bounds__(256) void ahat_kernel(const unsigned short* __restrict__ Shi,
                                                   const unsigned short* __restrict__ Slo,
                                                   float* __restrict__ out) {
  const int lane = threadIdx.x & 63;
  const int wid = threadIdx.x >> 6;
  const int brow = blockIdx.y * 128 + (wid >> 1) * 64;
  const int bcol = blockIdx.x * 128 + (wid & 1) * 64;
  const int r16 = lane & 15;
  const int koff = (lane >> 4) * 8;

  bf16x8 ahi[4][2], alo[4][2], bhi[4][2], blo[4][2];
#pragma unroll
  for (int m = 0; m < 4; ++m) {
#pragma unroll
    for (int ks = 0; ks < 2; ++ks) {
      size_t ai = (size_t)(brow + m * 16 + r16) * 64 + ks * 32 + koff;
      size_t bi = (size_t)(bcol + m * 16 + r16) * 64 + ks * 32 + koff;
      ahi[m][ks] = *reinterpret_cast<const bf16x8*>(&Shi[ai]);
      alo[m][ks] = *reinterpret_cast<const bf16x8*>(&Slo[ai]);
      bhi[m][ks] = *reinterpret_cast<const bf16x8*>(&Shi[bi]);
      blo[m][ks] = *reinterpret_cast<const bf16x8*>(&Slo[bi]);
    }
  }

  f32x4 acc[4][4];
#pragma unroll
  for (int m = 0; m < 4; ++m)
#pragma unroll
    for (int n = 0; n < 4; ++n) acc[m][n] = (f32x4){0.f, 0.f, 0.f, 0.f};

#pragma unroll
  for (int m = 0; m < 4; ++m)
#pragma unroll
    for (int n = 0; n < 4; ++n)
#pragma unroll
      for (int ks = 0; ks < 2; ++ks) {
        acc[m][n] = __builtin_amdgcn_mfma_f32_16x16x32_bf16(ahi[m][ks], bhi[n][ks], acc[m][n], 0, 0, 0);
        acc[m][n] = __builtin_amdgcn_mfma_f32_16x16x32_bf16(ahi[m][ks], blo[n][ks], acc[m][n], 0, 0, 0);
        acc[m][n] = __builtin_amdgcn_mfma_f32_16x16x32_bf16(alo[m][ks], bhi[n][ks], acc[m][n], 0, 0, 0);
      }

  const int crow0 = (lane >> 4) * 4;  // C/D: col=lane&15, row=(lane>>4)*4+reg  [m89]
#pragma unroll
  for (int m = 0; m < 4; ++m)
#pragma unroll
    for (int n = 0; n < 4; ++n)
#pragma unroll
      for (int r = 0; r < 4; ++r)
        out[(size_t)(brow + m * 16 + crow0 + r) * N_NODES + bcol + n * 16 + r16] = acc[m][n][r];
}

// ---------------- launch ----------------

extern "C" void kernel_launch(void* const* d_in, const int* in_sizes, int n_in,
                              void* d_out, int out_size, void* d_ws, size_t ws_size,
                              hipStream_t stream) {
  const float* x    = (const float*)d_in[0];
  const int*   ei   = (const int*)d_in[1];
  const float* W_e1 = (const float*)d_in[2];
  const float* b_e1 = (const float*)d_in[3];
  const float* W_e2 = (const float*)d_in[4];
  const float* b_e2 = (const float*)d_in[5];
  const float* W_a1 = (const float*)d_in[6];
  const float* b_a1 = (const float*)d_in[7];
  const float* W_a2 = (const float*)d_in[8];
  const float* b_a2 = (const float*)d_in[9];
  const float* W_s  = (const float*)d_in[10];
  const float* b_s  = (const float*)d_in[11];

  float* out_xhat = (float*)d_out;
  float* out_ahat = out_xhat + (size_t)N_NODES * 256;
  float* out_z    = out_ahat + (size_t)N_NODES * N_NODES;

  // Scratch that is DEAD before ahat_kernel launches lives inside the a_hat
  // output region (604 MB, written only by the final kernel). Only shi/slo/flag
  // (read DURING or deciding ahat inputs) live in d_ws (~3.2 MB).
  char* scr = (char*)out_ahat;
  size_t o = 0;
  auto alloc = [&](size_t bytes) -> void* {
    void* p = scr + o;
    o = (o + bytes + 255) & ~(size_t)255;
    return p;
  };
  int*   cnt      = (int*)alloc((size_t)N_NODES * 4);
  int*   csr_off  = (int*)alloc((size_t)(N_NODES + 1) * 4);
  int*   cursor   = (int*)alloc((size_t)N_NODES * 4);
  float* dinv     = (float*)alloc((size_t)N_NODES * 4);
  float* deg_inv  = (float*)alloc((size_t)N_NODES * 4);
  int*   csr_src  = (int*)alloc((size_t)N_EDGES * 4);
  float* csr_w    = (float*)alloc((size_t)N_EDGES * 4);
  float* P = (float*)alloc((size_t)N_NODES * 128 * 4);
  float* Q = (float*)alloc((size_t)N_NODES * 128 * 4);
  float* R = (float*)alloc((size_t)N_NODES * 128 * 4);
  float* S = (float*)alloc((size_t)N_NODES * 128 * 4);

  char* ws = (char*)d_ws;
  unsigned short* shi = (unsigned short*)ws;
  unsigned short* slo = shi + (size_t)N_NODES * 64;
  unsigned* eflag = (unsigned*)(slo + (size_t)N_NODES * 64);

  // graph prep (edge-width robust: int64-as-passed vs int32-converted)
  hipMemsetAsync(cnt, 0, (size_t)N_NODES * 4, stream);
  hipMemsetAsync(eflag, 0, 4, stream);
  detect_kernel<<<N_EDGES / 256, 256, 0, stream>>>((const unsigned*)ei, eflag);
  count_kernel<<<N_EDGES / 256, 256, 0, stream>>>(ei, eflag, cnt);
  scan_kernel<<<1, 1024, 0, stream>>>(cnt, csr_off, cursor, dinv, deg_inv);
  scatter_kernel<<<N_EDGES / 256, 256, 0, stream>>>(ei, eflag, dinv, cursor, csr_src, csr_w);

  // encoder layer 1: h1 = x@W_e1 ; h1a = relu(agg(h1)+b_e1)
  gemm_kernel<false, false><<<dim3(128 / 64, N_NODES / 64), 256, 0, stream>>>(x, W_e1, nullptr, P, 256, 128);
  agg_kernel<128, true, true><<<N_NODES / 2, 256, 0, stream>>>(P, csr_off, csr_src, csr_w, deg_inv, b_e1, Q);
  // encoder layer 2: h2 = h1a@W_e2 ; z = relu(agg(h2)+b_e2)
  gemm_kernel<false, false><<<dim3(64 / 64, N_NODES / 64), 256, 0, stream>>>(Q, W_e2, nullptr, R, 128, 64);
  agg_kernel<64, true, true><<<N_NODES / 4, 256, 0, stream>>>(R, csr_off, csr_src, csr_w, deg_inv, b_e2, out_z);
  // shared decoder aggregation: t_z = agg(z)   (linearity: agg(z@W) = agg(z)@W)
  agg_kernel<64, false, false><<<N_NODES / 4, 256, 0, stream>>>(out_z, csr_off, csr_src, csr_w, deg_inv, nullptr, P);
  // a = relu(t_z@W_a1+b_a1) ; s = relu(t_z@W_s+b_s)
  gemm_kernel<true, true><<<dim3(128 / 64, N_NODES / 64), 256, 0, stream>>>(P, W_a1, b_a1, Q, 64, 128);
  gemm_kernel<true, true><<<dim3(64 / 64, N_NODES / 64), 256, 0, stream>>>(P, W_s, b_s, R, 64, 64);
  // x_hat = agg(a)@W_a2 + b_a2
  agg_kernel<128, false, false><<<N_NODES / 2, 256, 0, stream>>>(Q, csr_off, csr_src, csr_w, deg_inv, nullptr, S);
  gemm_kernel<true, false><<<dim3(256 / 64, N_NODES / 64), 256, 0, stream>>>(S, W_a2, b_a2, out_xhat, 128, 256);
  // a_hat = s@s^T (split bf16, 3 MFMA products) — split BEFORE ahat overwrites scratch
  split_kernel<<<(N_NODES * 64) / 256, 256, 0, stream>>>(R, shi, slo);
  ahat_kernel<<<dim3(N_NODES / 128, N_NODES / 128), 256, 0, stream>>>(shi, slo, out_ahat);
}

// Round 6
// 956.472 us; speedup vs baseline: 1.0660x; 1.0660x over previous
//
#include <hip/hip_runtime.h>
#include <hip/hip_bf16.h>

#define N_NODES 12288
#define N_EDGES 393216

typedef __attribute__((ext_vector_type(8))) short bf16x8;
typedef __attribute__((ext_vector_type(4))) float f32x4;

// ---------------- edge-width detection ----------------
// Reference edge_index is int64. If the harness passes raw int64, every odd
// 32-bit word of the first E pairs is the (zero) high word; if converted to
// int32, those words are random src values. flag==0 => wide (int64) layout.

__global__ __launch_bounds__(256) void detect_kernel(const unsigned* __restrict__ w,
                                                     unsigned* __restrict__ flag) {
  int i = blockIdx.x * 256 + threadIdx.x;          // [0, N_EDGES)
  unsigned v = w[2 * i + 1];
  unsigned long long b = __ballot(v != 0);
  if ((threadIdx.x & 63) == 0 && b) atomicOr(flag, 1u);
}

// ---------------- graph prep ----------------

__global__ __launch_bounds__(256) void count_kernel(const int* __restrict__ ei,
                                                    const unsigned* __restrict__ flag,
                                                    int* __restrict__ cnt) {
  const bool wide = (*flag == 0);
  int e = blockIdx.x * 256 + threadIdx.x;
  int d = wide ? ei[2 * (N_EDGES + e)] : ei[N_EDGES + e];
  atomicAdd(&cnt[d], 1);
}

// single block, 1024 thr: exclusive scan of cnt -> csr_off/cursor + degree terms.
// Wave-shuffle scan: 3 barriers per 1024-chunk (12 chunks).
__global__ __launch_bounds__(1024) void scan_kernel(const int* __restrict__ cnt,
                                                    int* __restrict__ csr_off,
                                                    int* __restrict__ cursor,
                                                    float* __restrict__ dinv_sqrt,
                                                    float* __restrict__ deg_inv) {
  __shared__ int wsum[16];
  __shared__ int wpre[16];
  const int tid = threadIdx.x;
  const int lane = tid & 63;
  const int wid = tid >> 6;
  int carry = 0;
  for (int base = 0; base < N_NODES; base += 1024) {
    int i = base + tid;                       // N_NODES % 1024 == 0
    int c = cnt[i];
    float dg = (float)(c + 1);                // deg includes self-loop
    dinv_sqrt[i] = rsqrtf(dg);
    deg_inv[i] = 1.0f / dg;
    // wave-inclusive scan
    int v = c;
#pragma unroll
    for (int d = 1; d < 64; d <<= 1) {
      int t = __shfl_up(v, d);
      if (lane >= d) v += t;
    }
    if (lane == 63) wsum[wid] = v;
    __syncthreads();
    if (tid < 16) {
      int t = wsum[tid];
#pragma unroll
      for (int d = 1; d < 16; d <<= 1) {
        int u = __shfl_up(t, d);
        if (tid >= d) t += u;
      }
      wpre[tid] = t;
    }
    __syncthreads();
    int incl = carry + (wid ? wpre[wid - 1] : 0) + v;
    int excl = incl - c;
    csr_off[i] = excl;
    cursor[i] = excl;
    carry += wpre[15];
    __syncthreads();                          // protect wsum before next chunk
  }
  if (tid == 0) csr_off[N_NODES] = carry;
}

__global__ __launch_bounds__(256) void scatter_kernel(const int* __restrict__ ei,
                                                      const unsigned* __restrict__ flag,
                                                      const float* __restrict__ dinv_sqrt,
                                                      int* __restrict__ cursor,
                                                      int* __restrict__ csr_src,
                                                      float* __restrict__ csr_w) {
  const bool wide = (*flag == 0);
  int e = blockIdx.x * 256 + threadIdx.x;
  int s = wide ? ei[2 * e] : ei[e];
  int d = wide ? ei[2 * (N_EDGES + e)] : ei[N_EDGES + e];
  int p = atomicAdd(&cursor[d], 1);
  csr_src[p] = s;
  csr_w[p] = dinv_sqrt[s] * dinv_sqrt[d];
}

// ---------------- bf16 split helper ----------------

__device__ __forceinline__ unsigned short f32_to_bf16_rn(float v) {
  unsigned int u = __float_as_uint(v);
  u += 0x7FFFu + ((u >> 16) & 1u);
  return (unsigned short)(u >> 16);
}

// ---------------- dense fp32 GEMM: C[M,Nf] = A[M,K]@B[K,Nf] (+bias, relu) ----------------
// grid = (Nf/64, M/64), block = 256. BM=BN=64, BK=16, 4x4 microtile.
// SPLIT: instead of writing C, write bf16 hi/lo decomposition (for s @ s^T).

template <bool BIAS, bool RELU, bool SPLIT>
__global__ __launch_bounds__(256) void gemm_kernel(const float* __restrict__ A,
                                                   const float* __restrict__ B,
                                                   const float* __restrict__ bias,
                                                   float* __restrict__ C,
                                                   unsigned short* __restrict__ hi,
                                                   unsigned short* __restrict__ lo,
                                                   int K, int Nf) {
  __shared__ float As[16][65];
  __shared__ float Bs[16][68];
  const int tid = threadIdx.x;
  const int bm = blockIdx.y * 64;
  const int bn = blockIdx.x * 64;
  const int tr = (tid >> 4) * 4;
  const int tc = (tid & 15) * 4;
  const int lm = tid >> 2;          // A-load row 0..63
  const int lk = (tid & 3) * 4;     // A-load k 0,4,8,12
  const int lbk = tid >> 4;         // B-load k 0..15
  const int lbc = (tid & 15) * 4;   // B-load col
  float acc[4][4] = {};
  for (int k0 = 0; k0 < K; k0 += 16) {
    float4 a4 = *reinterpret_cast<const float4*>(&A[(size_t)(bm + lm) * K + k0 + lk]);
    float4 b4 = *reinterpret_cast<const float4*>(&B[(size_t)(k0 + lbk) * Nf + bn + lbc]);
    As[lk + 0][lm] = a4.x; As[lk + 1][lm] = a4.y; As[lk + 2][lm] = a4.z; As[lk + 3][lm] = a4.w;
    Bs[lbk][lbc + 0] = b4.x; Bs[lbk][lbc + 1] = b4.y; Bs[lbk][lbc + 2] = b4.z; Bs[lbk][lbc + 3] = b4.w;
    __syncthreads();
#pragma unroll
    for (int kk = 0; kk < 16; ++kk) {
      float av[4], bv[4];
#pragma unroll
      for (int i = 0; i < 4; ++i) av[i] = As[kk][tr + i];
#pragma unroll
      for (int j = 0; j < 4; ++j) bv[j] = Bs[kk][tc + j];
#pragma unroll
      for (int i = 0; i < 4; ++i)
#pragma unroll
        for (int j = 0; j < 4; ++j) acc[i][j] = fmaf(av[i], bv[j], acc[i][j]);
    }
    __syncthreads();
  }
#pragma unroll
  for (int i = 0; i < 4; ++i) {
    float v[4];
#pragma unroll
    for (int j = 0; j < 4; ++j) {
      float t = acc[i][j];
      if (BIAS) t += bias[bn + tc + j];
      if (RELU) t = fmaxf(t, 0.0f);
      v[j] = t;
    }
    if (!SPLIT) {
      float4 o; o.x = v[0]; o.y = v[1]; o.z = v[2]; o.w = v[3];
      *reinterpret_cast<float4*>(&C[(size_t)(bm + tr + i) * Nf + bn + tc]) = o;
    } else {
      ushort4 h4, l4;
      unsigned short* hp = (unsigned short*)&h4;
      unsigned short* lp = (unsigned short*)&l4;
#pragma unroll
      for (int j = 0; j < 4; ++j) {
        unsigned short h = f32_to_bf16_rn(v[j]);
        float hf = __uint_as_float(((unsigned int)h) << 16);
        hp[j] = h;
        lp[j] = f32_to_bf16_rn(v[j] - hf);
      }
      size_t off = (size_t)(bm + tr + i) * Nf + bn + tc;
      *reinterpret_cast<ushort4*>(&hi[off]) = h4;
      *reinterpret_cast<ushort4*>(&lo[off]) = l4;
    }
  }
}

// ---------------- GCN aggregation (dst-centric, CSR, 64-wide f-passes) ----------------
// out[i,f] = sum_e w_e * H[src_e, f] + deg_inv[i]*H[i,f] (+bias, relu)
// blockIdx.y picks the 64-feature slice -> per-pass gather working set 3.1 MB
// (fits per-XCD 4 MiB L2). 4-deep edge unroll for gather-latency overlap.

template <bool BIAS, bool RELU>
__global__ __launch_bounds__(256) void agg_kernel(const float* __restrict__ H,
                                                  const int* __restrict__ csr_off,
                                                  const int* __restrict__ csr_src,
                                                  const float* __restrict__ csr_w,
                                                  const float* __restrict__ deg_inv,
                                                  const float* __restrict__ bias,
                                                  float* __restrict__ out,
                                                  int Fs) {
  const int node = blockIdx.x * 4 + (threadIdx.x >> 6);
  const int f = blockIdx.y * 64 + (threadIdx.x & 63);
  const int p0 = csr_off[node];
  const int p1 = csr_off[node + 1];
  float acc = deg_inv[node] * H[(size_t)node * Fs + f];
  int p = p0;
  for (; p + 3 < p1; p += 4) {
    int s0 = csr_src[p];     float w0 = csr_w[p];
    int s1 = csr_src[p + 1]; float w1 = csr_w[p + 1];
    int s2 = csr_src[p + 2]; float w2 = csr_w[p + 2];
    int s3 = csr_src[p + 3]; float w3 = csr_w[p + 3];
    float h0 = H[(size_t)s0 * Fs + f];
    float h1 = H[(size_t)s1 * Fs + f];
    float h2 = H[(size_t)s2 * Fs + f];
    float h3 = H[(size_t)s3 * Fs + f];
    acc = fmaf(w0, h0, acc);
    acc = fmaf(w1, h1, acc);
    acc = fmaf(w2, h2, acc);
    acc = fmaf(w3, h3, acc);
  }
  for (; p < p1; ++p) acc = fmaf(csr_w[p], H[(size_t)csr_src[p] * Fs + f], acc);
  if (BIAS) acc += bias[f];
  if (RELU) acc = fmaxf(acc, 0.0f);
  out[(size_t)node * Fs + f] = acc;
}

// ---------------- a_hat = s @ s^T via split-bf16 MFMA ----------------
// block = 256 (4 waves, 2x2), wave computes 64x64; block tile 128x128.
// XCD-aware swizzle (9216 blocks % 8 == 0 -> bijective).

__global__ __launch_bounds__(256) void ahat_kernel(const unsigned short* __restrict__ Shi,
                                                   const unsigned short* __restrict__ Slo,
                                                   float* __restrict__ out) {
  const int GW = N_NODES / 128;                 // 96
  int flat = blockIdx.y * GW + blockIdx.x;
  const int NWG = GW * GW;                      // 9216
  int sw = (flat & 7) * (NWG / 8) + (flat >> 3);
  const int bx = sw % GW;
  const int by = sw / GW;

  const int lane = threadIdx.x & 63;
  const int wid = threadIdx.x >> 6;
  const int brow = by * 128 + (wid >> 1) * 64;
  const int bcol = bx * 128 + (wid & 1) * 64;
  const int r16 = lane & 15;
  const int koff = (lane >> 4) * 8;

  bf16x8 ahi[4][2], alo[4][2], bhi[4][2], blo[4][2];
#pragma unroll
  for (int m = 0; m < 4; ++m) {
#pragma unroll
    for (int ks = 0; ks < 2; ++ks) {
      size_t ai = (size_t)(brow + m * 16 + r16) * 64 + ks * 32 + koff;
      size_t bi = (size_t)(bcol + m * 16 + r16) * 64 + ks * 32 + koff;
      ahi[m][ks] = *reinterpret_cast<const bf16x8*>(&Shi[ai]);
      alo[m][ks] = *reinterpret_cast<const bf16x8*>(&Slo[ai]);
      bhi[m][ks] = *reinterpret_cast<const bf16x8*>(&Shi[bi]);
      blo[m][ks] = *reinterpret_cast<const bf16x8*>(&Slo[bi]);
    }
  }

  f32x4 acc[4][4];
#pragma unroll
  for (int m = 0; m < 4; ++m)
#pragma unroll
    for (int n = 0; n < 4; ++n) acc[m][n] = (f32x4){0.f, 0.f, 0.f, 0.f};

#pragma unroll
  for (int m = 0; m < 4; ++m)
#pragma unroll
    for (int n = 0; n < 4; ++n)
#pragma unroll
      for (int ks = 0; ks < 2; ++ks) {
        acc[m][n] = __builtin_amdgcn_mfma_f32_16x16x32_bf16(ahi[m][ks], bhi[n][ks], acc[m][n], 0, 0, 0);
        acc[m][n] = __builtin_amdgcn_mfma_f32_16x16x32_bf16(ahi[m][ks], blo[n][ks], acc[m][n], 0, 0, 0);
        acc[m][n] = __builtin_amdgcn_mfma_f32_16x16x32_bf16(alo[m][ks], bhi[n][ks], acc[m][n], 0, 0, 0);
      }

  const int crow0 = (lane >> 4) * 4;  // C/D: col=lane&15, row=(lane>>4)*4+reg  [m89]
#pragma unroll
  for (int m = 0; m < 4; ++m)
#pragma unroll
    for (int n = 0; n < 4; ++n)
#pragma unroll
      for (int r = 0; r < 4; ++r)
        out[(size_t)(brow + m * 16 + crow0 + r) * N_NODES + bcol + n * 16 + r16] = acc[m][n][r];
}

// ---------------- launch ----------------

extern "C" void kernel_launch(void* const* d_in, const int* in_sizes, int n_in,
                              void* d_out, int out_size, void* d_ws, size_t ws_size,
                              hipStream_t stream) {
  const float* x    = (const float*)d_in[0];
  const int*   ei   = (const int*)d_in[1];
  const float* W_e1 = (const float*)d_in[2];
  const float* b_e1 = (const float*)d_in[3];
  const float* W_e2 = (const float*)d_in[4];
  const float* b_e2 = (const float*)d_in[5];
  const float* W_a1 = (const float*)d_in[6];
  const float* b_a1 = (const float*)d_in[7];
  const float* W_a2 = (const float*)d_in[8];
  const float* b_a2 = (const float*)d_in[9];
  const float* W_s  = (const float*)d_in[10];
  const float* b_s  = (const float*)d_in[11];

  float* out_xhat = (float*)d_out;
  float* out_ahat = out_xhat + (size_t)N_NODES * 256;
  float* out_z    = out_ahat + (size_t)N_NODES * N_NODES;

  // Scratch that is DEAD before ahat_kernel launches lives inside the a_hat
  // output region (604 MB, written only by the final kernel). Only shi/slo
  // (read DURING ahat_kernel) live in d_ws (~3.2 MB).
  char* scr = (char*)out_ahat;
  size_t o = 0;
  auto alloc = [&](size_t bytes) -> void* {
    void* p = scr + o;
    o = (o + bytes + 255) & ~(size_t)255;
    return p;
  };
  int*   cnt      = (int*)alloc((size_t)(N_NODES + 64) * 4);  // +eflag tail
  unsigned* eflag = (unsigned*)(cnt + N_NODES);
  int*   csr_off  = (int*)alloc((size_t)(N_NODES + 1) * 4);
  int*   cursor   = (int*)alloc((size_t)N_NODES * 4);
  float* dinv     = (float*)alloc((size_t)N_NODES * 4);
  float* deg_inv  = (float*)alloc((size_t)N_NODES * 4);
  int*   csr_src  = (int*)alloc((size_t)N_EDGES * 4);
  float* csr_w    = (float*)alloc((size_t)N_EDGES * 4);
  float* P = (float*)alloc((size_t)N_NODES * 128 * 4);
  float* Q = (float*)alloc((size_t)N_NODES * 128 * 4);
  float* R = (float*)alloc((size_t)N_NODES * 128 * 4);
  float* S = (float*)alloc((size_t)N_NODES * 128 * 4);

  char* ws = (char*)d_ws;
  unsigned short* shi = (unsigned short*)ws;
  unsigned short* slo = shi + (size_t)N_NODES * 64;

  // graph prep (edge-width robust: int64-as-passed vs int32-converted)
  hipMemsetAsync(cnt, 0, (size_t)(N_NODES + 1) * 4, stream);   // cnt + eflag
  detect_kernel<<<N_EDGES / 256, 256, 0, stream>>>((const unsigned*)ei, eflag);
  count_kernel<<<N_EDGES / 256, 256, 0, stream>>>(ei, eflag, cnt);
  scan_kernel<<<1, 1024, 0, stream>>>(cnt, csr_off, cursor, dinv, deg_inv);
  scatter_kernel<<<N_EDGES / 256, 256, 0, stream>>>(ei, eflag, dinv, cursor, csr_src, csr_w);

  // encoder layer 1: h1 = x@W_e1 ; h1a = relu(agg(h1)+b_e1)
  gemm_kernel<false, false, false><<<dim3(2, 192), 256, 0, stream>>>(x, W_e1, nullptr, P, nullptr, nullptr, 256, 128);
  agg_kernel<true, true><<<dim3(N_NODES / 4, 2), 256, 0, stream>>>(P, csr_off, csr_src, csr_w, deg_inv, b_e1, Q, 128);
  // encoder layer 2: h2 = h1a@W_e2 ; z = relu(agg(h2)+b_e2)
  gemm_kernel<false, false, false><<<dim3(1, 192), 256, 0, stream>>>(Q, W_e2, nullptr, R, nullptr, nullptr, 128, 64);
  agg_kernel<true, true><<<dim3(N_NODES / 4, 1), 256, 0, stream>>>(R, csr_off, csr_src, csr_w, deg_inv, b_e2, out_z, 64);
  // shared decoder aggregation: t_z = agg(z)   (linearity: agg(z@W) = agg(z)@W)
  agg_kernel<false, false><<<dim3(N_NODES / 4, 1), 256, 0, stream>>>(out_z, csr_off, csr_src, csr_w, deg_inv, nullptr, P, 64);
  // a = relu(t_z@W_a1+b_a1) ; s = relu(t_z@W_s+b_s) -> fused bf16 hi/lo split
  gemm_kernel<true, true, false><<<dim3(2, 192), 256, 0, stream>>>(P, W_a1, b_a1, Q, nullptr, nullptr, 64, 128);
  gemm_kernel<true, true, true><<<dim3(1, 192), 256, 0, stream>>>(P, W_s, b_s, nullptr, shi, slo, 64, 64);
  // x_hat = agg(a)@W_a2 + b_a2
  agg_kernel<false, false><<<dim3(N_NODES / 4, 2), 256, 0, stream>>>(Q, csr_off, csr_src, csr_w, deg_inv, nullptr, S, 128);
  gemm_kernel<true, false, false><<<dim3(4, 192), 256, 0, stream>>>(S, W_a2, b_a2, out_xhat, nullptr, nullptr, 128, 256);
  // a_hat = s@s^T (split bf16, 3 MFMA products)
  ahat_kernel<<<dim3(N_NODES / 128, N_NODES / 128), 256, 0, stream>>>(shi, slo, out_ahat);
}